// Round 6
// baseline (95.066 us; speedup 1.0000x reference)
//
#include <hip/hip_runtime.h>
#include <hip/hip_bf16.h>

// ---- problem constants ----
#define B_IMG   128
#define CH      3
#define HW      224
#define NPATCH  196          // tokens per image
#define TOKENS  25088        // B_IMG * NPATCH
#define PATCH   16
#define FDIM    768          // C*P*P (K of the GEMM)
#define DDIM    768          // output embed dim (N of the GEMM)
#define TOKELEMS ((size_t)TOKENS * FDIM)
#define OUT_TOKENS ((size_t)TOKENS * DDIM)     // positions follow in d_out

#define GATHER_BLOCKS (TOKENS * (FDIM / 4) / 256)   // 18816
#define WCONV_BLOCKS  ((DDIM * FDIM / 4) / 256)     // 576

typedef short short8 __attribute__((ext_vector_type(8)));
typedef float f32x4  __attribute__((ext_vector_type(4)));

static __device__ __forceinline__ unsigned short f2bf(float v) {
  unsigned u = __float_as_uint(v);
  unsigned r = u + 0x7fffu + ((u >> 16) & 1u);
  return (unsigned short)(r >> 16);
}

static __device__ __forceinline__ void gload16(const short* g, short* l) {
  __builtin_amdgcn_global_load_lds(
      (const __attribute__((address_space(1))) void*)g,
      (__attribute__((address_space(3))) void*)l,
      16, 0, 0);
}

// ---- kernel 1: gather patches -> bf16 [TOKENS][768] + positions, W -> bf16 ----
__global__ __launch_bounds__(256) void prep_kernel(
    const float* __restrict__ x, const int* __restrict__ ys,
    const int* __restrict__ xs, const float* __restrict__ W,
    short* __restrict__ patches, short* __restrict__ Wbf,
    float* __restrict__ pos) {
  const int blk = blockIdx.x;
  if (blk < GATHER_BLOCKS) {
    int e   = blk * 256 + threadIdx.x;      // quad index
    int tok = e / 192;
    int q   = e - tok * 192;
    int f   = q * 4;
    int b   = tok / NPATCH;
    int y   = ys[tok];
    int xc  = xs[tok];
    int c   = f >> 8;
    int rem = f & 255;
    int py  = rem >> 4;
    int px  = rem & 15;
    const float* src = x + ((size_t)(b * CH + c) * HW + (y + py)) * HW + xc + px;
    ushort4 o;
    o.x = f2bf(src[0]); o.y = f2bf(src[1]); o.z = f2bf(src[2]); o.w = f2bf(src[3]);
    *(ushort4*)&patches[(size_t)tok * FDIM + f] = o;
    if (q == 0) {
      pos[(size_t)tok * 2]     = (float)y;
      pos[(size_t)tok * 2 + 1] = (float)xc;
    }
  } else {
    int i = ((blk - GATHER_BLOCKS) * 256 + threadIdx.x) * 4;
    float4 v = *(const float4*)&W[i];
    ushort4 o;
    o.x = f2bf(v.x); o.y = f2bf(v.y); o.z = f2bf(v.z); o.w = f2bf(v.w);
    *(ushort4*)&Wbf[i] = o;
  }
}

// ---- kernel 2: 256x256 8-phase GEMM (m201 template port) ----
// 8 waves 2M x 4N (wave tile 128x64), BK=64, 2-dbuf x 2-half LDS (128KB),
// st_16x32 XOR swizzle both-sides, per-phase {ds_read || stage -> bar ->
// lgkm0 -> 16 MFMA -> bar}, vmcnt(6) once per K-tile (3 half-tiles in
// flight), T5 setprio.
#define MF(ACC, AF, BF) \
  ACC = __builtin_amdgcn_mfma_f32_16x16x32_bf16(AF, BF, ACC, 0, 0, 0)

__global__ __launch_bounds__(512, 2) void gemm_kernel(
    const short* __restrict__ A,    // patches bf16 [TOKENS][768]
    const short* __restrict__ Bw,   // Wbf bf16 [768][768]
    const float* __restrict__ bias,
    float* __restrict__ C) {
  __shared__ short As[2][2][128 * 64];   // [dbuf][half(128 rows)][row*64+col]
  __shared__ short Bs[2][2][128 * 64];

  const int tid = threadIdx.x;
  const int w   = tid >> 6;      // 0..7
  const int l   = tid & 63;
  const int wr  = w >> 2;        // 0..1 : M half (128 rows)
  const int wc  = w & 3;         // 0..3 : N quarter (64 cols)
  const int lr  = l & 15;
  const int lg  = l >> 4;

  // bijective XCD swizzle, 294 blocks = 6 chunks of 37 + 2 of 36
  const int id   = blockIdx.x;
  const int xcd  = id & 7;
  const int chnk = id >> 3;
  const int nid  = (xcd < 6 ? xcd * 37 : 6 * 37 + (xcd - 6) * 36) + chnk;
  const int mt   = nid / 3;
  const int nt   = nid - mt * 3;
  const int m0   = mt * 256;
  const int n0   = nt * 256;

  // bias pinned complete before staging (keeps the vmcnt ledger clean)
  float bs[4];
#pragma unroll
  for (int ni = 0; ni < 4; ++ni)
    bs[ni] = bias[n0 + wc * 64 + ni * 16 + lr];
#pragma unroll
  for (int ni = 0; ni < 4; ++ni) asm volatile("" : "+v"(bs[ni]));

  f32x4 acc[8][4];
  const f32x4 z = {0.f, 0.f, 0.f, 0.f};
#pragma unroll
  for (int mi = 0; mi < 8; ++mi)
#pragma unroll
    for (int ni = 0; ni < 4; ++ni) acc[mi][ni] = z;

  // ---- staging: half-tile = 128 rows x 64 cols bf16 = 16KB; per thread 2
  // gload16 (pass 0: rows w*8+(l>>3), pass 1: +64). Global source column is
  // PRE-SWIZZLED (st_16x32: lanes 32-63 swap 16-elem blocks) so the linear
  // gload_lds dest yields a swizzled LDS image (rule #21: both sides).
  const int srow = w * 8 + (l >> 3);
  const int scol = ((l & 7) * 8) ^ (((l >> 5) & 1) * 16);
  auto stA = [&](int buf, int half, int kt) {
    const short* src = A + (size_t)(m0 + half * 128 + srow) * FDIM + kt * 64 + scol;
    short* dst = &As[buf][half][(w * 8) * 64];
    gload16(src, dst);
    gload16(src + 64 * FDIM, dst + 64 * 64);
  };
  auto stB = [&](int buf, int half, int kt) {
    const short* src = Bw + (size_t)(n0 + half * 128 + srow) * FDIM + kt * 64 + scol;
    short* dst = &Bs[buf][half][(w * 8) * 64];
    gload16(src, dst);
    gload16(src + 64 * FDIM, dst + 64 * 64);
  };

  // ---- swizzled fragment reads: logical (row, ks*32+lg*8) lives at
  // col ^ ((row&4)?16:0); row&4 == lr&4 for all our frag rows.
  const int rk0 = (lg * 8) ^ ((lr & 4) ? 16 : 0);
  const int rk1 = (32 + lg * 8) ^ ((lr & 4) ? 16 : 0);
  auto rdA = [&](int buf, int mi, int ks) {
    return *(const short8*)&As[buf][wr][(mi * 16 + lr) * 64 + (ks ? rk1 : rk0)];
  };
  auto rdB = [&](int buf, int ni, int ks) {
    return *(const short8*)&Bs[buf][wc >> 1]
        [((wc & 1) * 64 + ni * 16 + lr) * 64 + (ks ? rk1 : rk0)];
  };

  short8 af[4][2], ag[4][2], bf[4][2];

  // Region-death schedule (verified): Blo read fully at phase A (wc<2 reads
  // all b), Bhi at A+B, Alo/Ahi at A+B. Stage slots: A: Bhi(t+1)[other buf],
  // B: Blo(t+2), C: Alo(t+2), D: Ahi(t+2) — every overwrite is >=2 barriers
  // + lgkm0 after the region's last read => race-free.
  auto tile = [&](int t, int c, int cn, bool sA_, bool sBCD) {
    // ---------- phase A : reads a0-3 + b (all for wc<2, b0-1 for wc>=2)
#pragma unroll
    for (int mi = 0; mi < 4; ++mi) {
      af[mi][0] = rdA(c, mi, 0); af[mi][1] = rdA(c, mi, 1);
    }
    if (wc < 2) {
#pragma unroll
      for (int ni = 0; ni < 4; ++ni) {
        bf[ni][0] = rdB(c, ni, 0); bf[ni][1] = rdB(c, ni, 1);
      }
    } else {
#pragma unroll
      for (int ni = 0; ni < 2; ++ni) {
        bf[ni][0] = rdB(c, ni, 0); bf[ni][1] = rdB(c, ni, 1);
      }
    }
    if (sA_) stB(cn, 1, t + 1);
    __builtin_amdgcn_s_barrier();
    asm volatile("s_waitcnt lgkmcnt(0)" ::: "memory");
    __builtin_amdgcn_sched_barrier(0);
    __builtin_amdgcn_s_setprio(1);
#pragma unroll
    for (int mi = 0; mi < 4; ++mi)
#pragma unroll
      for (int ni = 0; ni < 2; ++ni) {
        MF(acc[mi][ni], af[mi][0], bf[ni][0]);
        MF(acc[mi][ni], af[mi][1], bf[ni][1]);
      }
    __builtin_amdgcn_s_setprio(0);
    __builtin_amdgcn_s_barrier();
    __builtin_amdgcn_sched_barrier(0);
    // ---------- phase B : reads a4-7 (+ b2-3 for wc>=2)
#pragma unroll
    for (int mi = 0; mi < 4; ++mi) {
      ag[mi][0] = rdA(c, mi + 4, 0); ag[mi][1] = rdA(c, mi + 4, 1);
    }
    if (wc >= 2) {
#pragma unroll
      for (int ni = 2; ni < 4; ++ni) {
        bf[ni][0] = rdB(c, ni, 0); bf[ni][1] = rdB(c, ni, 1);
      }
    }
    if (sBCD) stB(c, 0, t + 2);
    __builtin_amdgcn_s_barrier();
    asm volatile("s_waitcnt lgkmcnt(0)" ::: "memory");
    __builtin_amdgcn_sched_barrier(0);
    __builtin_amdgcn_s_setprio(1);
#pragma unroll
    for (int mi = 0; mi < 4; ++mi)
#pragma unroll
      for (int ni = 0; ni < 2; ++ni) {
        MF(acc[mi + 4][ni], ag[mi][0], bf[ni][0]);
        MF(acc[mi + 4][ni], ag[mi][1], bf[ni][1]);
      }
    __builtin_amdgcn_s_setprio(0);
    __builtin_amdgcn_s_barrier();
    __builtin_amdgcn_sched_barrier(0);
    // ---------- phase C : no reads
    if (sBCD) stA(c, 0, t + 2);
    __builtin_amdgcn_s_barrier();
    __builtin_amdgcn_s_setprio(1);
#pragma unroll
    for (int mi = 0; mi < 4; ++mi)
#pragma unroll
      for (int ni = 2; ni < 4; ++ni) {
        MF(acc[mi][ni], af[mi][0], bf[ni][0]);
        MF(acc[mi][ni], af[mi][1], bf[ni][1]);
      }
    __builtin_amdgcn_s_setprio(0);
    __builtin_amdgcn_s_barrier();
    __builtin_amdgcn_sched_barrier(0);
    // ---------- phase D : no reads
    if (sBCD) stA(c, 1, t + 2);
    __builtin_amdgcn_s_barrier();
    __builtin_amdgcn_s_setprio(1);
#pragma unroll
    for (int mi = 0; mi < 4; ++mi)
#pragma unroll
      for (int ni = 2; ni < 4; ++ni) {
        MF(acc[mi + 4][ni], ag[mi][0], bf[ni][0]);
        MF(acc[mi + 4][ni], ag[mi][1], bf[ni][1]);
      }
    __builtin_amdgcn_s_setprio(0);
    // caller emits vmcnt + trailing barrier
  };

  // prologue: tile 0 fully + 3 halves of tile 1 (14 loads)
  stB(0, 0, 0);   // Blo(0)
  stA(0, 0, 0);   // Alo(0)
  stA(0, 1, 0);   // Ahi(0)
  stB(0, 1, 0);   // Bhi(0)
  stB(1, 0, 1);   // Blo(1)
  stA(1, 0, 1);   // Alo(1)
  stA(1, 1, 1);   // Ahi(1)
  asm volatile("s_waitcnt vmcnt(6)" ::: "memory");   // tile 0 landed
  __builtin_amdgcn_s_barrier();
  __builtin_amdgcn_sched_barrier(0);

#pragma unroll 1
  for (int tt = 0; tt < 5; ++tt) {
    const int t0 = tt * 2;
    tile(t0, 0, 1, true, true);
    asm volatile("s_waitcnt vmcnt(6)" ::: "memory");
    __builtin_amdgcn_s_barrier();
    __builtin_amdgcn_sched_barrier(0);
    tile(t0 + 1, 1, 0, true, true);
    asm volatile("s_waitcnt vmcnt(6)" ::: "memory");
    __builtin_amdgcn_s_barrier();
    __builtin_amdgcn_sched_barrier(0);
  }
  tile(10, 0, 1, true, false);
  asm volatile("s_waitcnt vmcnt(0)" ::: "memory");
  __builtin_amdgcn_s_barrier();
  __builtin_amdgcn_sched_barrier(0);
  tile(11, 1, 0, false, false);

  // epilogue: C/D layout col = lane&15, row = (lane>>4)*4 + j
#pragma unroll
  for (int ni = 0; ni < 4; ++ni) {
    const int col = n0 + wc * 64 + ni * 16 + lr;
#pragma unroll
    for (int mi = 0; mi < 8; ++mi) {
      const int row = m0 + wr * 128 + mi * 16 + lg * 4;
      const f32x4 v = acc[mi][ni];
#pragma unroll
      for (int j = 0; j < 4; ++j)
        C[(size_t)(row + j) * DDIM + col] = v[j] + bs[ni];
    }
  }
}

// ---- fallback (ws too small): naive fused f32, correct but slow ----
__global__ __launch_bounds__(256) void naive_kernel(
    const float* __restrict__ x, const int* __restrict__ ys,
    const int* __restrict__ xs, const float* __restrict__ W,
    const float* __restrict__ bias, float* __restrict__ out) {
  __shared__ float prow[FDIM];
  const int tok = blockIdx.x;
  const int t   = threadIdx.x;
  const int b   = tok / NPATCH;
  const int y   = ys[tok];
  const int xc  = xs[tok];
  for (int i = t; i < FDIM; i += 256) {
    int c = i >> 8, rem = i & 255, py = rem >> 4, px = rem & 15;
    prow[i] = x[((size_t)(b * CH + c) * HW + y + py) * HW + xc + px];
  }
  __syncthreads();
  for (int dd = 0; dd < 3; ++dd) {
    const int d = t + dd * 256;
    float s = bias[d];
    const float4* wr = (const float4*)&W[(size_t)d * FDIM];
    const float4* pr = (const float4*)prow;
    for (int f4 = 0; f4 < FDIM / 4; ++f4) {
      float4 wv = wr[f4];
      float4 pv = pr[f4];
      s += wv.x * pv.x + wv.y * pv.y + wv.z * pv.z + wv.w * pv.w;
    }
    out[(size_t)tok * DDIM + d] = s;
  }
  if (t == 0) {
    float* pos = out + OUT_TOKENS;
    pos[(size_t)tok * 2]     = (float)y;
    pos[(size_t)tok * 2 + 1] = (float)xc;
  }
}

extern "C" void kernel_launch(void* const* d_in, const int* in_sizes, int n_in,
                              void* d_out, int out_size, void* d_ws, size_t ws_size,
                              hipStream_t stream) {
  const float* x    = (const float*)d_in[0];
  const int*   ys   = (const int*)d_in[1];
  const int*   xs   = (const int*)d_in[2];
  const float* W    = (const float*)d_in[3];
  const float* bias = (const float*)d_in[4];
  float* out = (float*)d_out;
  float* pos = out + OUT_TOKENS;

  const size_t w_bytes = (size_t)DDIM * FDIM * 2;
  const size_t p_bytes = TOKELEMS * 2;
  if (ws_size >= w_bytes + p_bytes) {
    short* Wbf     = (short*)d_ws;
    short* patches = (short*)d_ws + (size_t)DDIM * FDIM;
    prep_kernel<<<GATHER_BLOCKS + WCONV_BLOCKS, 256, 0, stream>>>(
        x, ys, xs, W, patches, Wbf, pos);
    gemm_kernel<<<(TOKENS / 256) * (DDIM / 256), 512, 0, stream>>>(
        patches, Wbf, bias, out);
  } else {
    naive_kernel<<<TOKENS, 256, 0, stream>>>(x, ys, xs, W, bias, out);
  }
}